// Round 6
// baseline (107.100 us; speedup 1.0000x reference)
//
#include <hip/hip_runtime.h>
#include <hip/hip_bf16.h>

#define N 4096
#define D 512
#define MARGIN 0.5f
#define BETA 10.0f
#define TB 64                      // tile size (was 128)
#define NTILE (N / TB)             // 64
#define NBLOCKS (NTILE * (NTILE + 1) / 2)   // 2080 upper-triangle tiles

typedef __attribute__((ext_vector_type(8))) short short8;
typedef __attribute__((ext_vector_type(4))) float floatx4;

__device__ inline unsigned short f2bf(float f) {
    unsigned u = __float_as_uint(f);
    u += 0x7fffu + ((u >> 16) & 1u);   // round-to-nearest-even
    return (unsigned short)(u >> 16);
}

// ---- Kernel 1: f32 -> bf16 convert + zero the accumulator buffers ----
__global__ __launch_bounds__(256) void convert_bf16_kernel(
        const float4* __restrict__ in, ushort4* __restrict__ out,
        float* __restrict__ sums /* 2*N floats to zero */) {
    int idx = blockIdx.x * 256 + threadIdx.x;
    if (idx < 2 * N) sums[idx] = 0.f;
    float4 v = in[idx];
    ushort4 o;
    o.x = f2bf(v.x); o.y = f2bf(v.y); o.z = f2bf(v.z); o.w = f2bf(v.w);
    out[idx] = o;
}

// ---- Kernel 2: fused sim-GEMM + masked exp sums, UPPER-TRIANGLE only ----
//
// HISTORY (do not regress):
//  - K-loop sync: R2's __syncthreads() 2-phase dbuf schedule. Counted-vmcnt
//    raw barriers (R3) regressed 4x (compiler re-inserts vmcnt(0) before
//    ds_reads). Do not touch.
//  - Finalize fusion: tried (R3-R5). Per-block device-fence thrashed L2
//    (+28us); scoped variant still +4.7us (every block drains vmcnt(0) on
//    contended atomics). Separate finalize launch is cheaper. Reverted.
//  - R6: 64x64 tiles (was 128x128). Cross-round arithmetic pinned the
//    128-tile GEMM at ~31-36us vs ~3us MFMA content: latency-bound at
//    2.06 blocks/CU. 64x64 -> 2080 blocks (8.1/CU), LDS 16.5KB,
//    acc[2][2]; per-step barrier stalls now hidden by other blocks (TLP).
//    All swizzle formulas carry over (row bases stay multiples of 16).
__global__ __launch_bounds__(256, 8) void ms_loss_gemm(
        const unsigned short* __restrict__ Ebf,
        const int* __restrict__ labels,
        float* __restrict__ pos_sum,
        float* __restrict__ neg_sum) {
    __shared__ unsigned short Atile[2][TB * 32];   // 2 x 4 KB
    __shared__ unsigned short Btile[2][TB * 32];   // 2 x 4 KB
    __shared__ int rlab[TB];
    __shared__ int clab[TB];

    // decode linear block id -> upper-triangle tile (bi, bj), bi <= bj
    int t = blockIdx.x;
    int bi = 0;
    while (t >= (NTILE - bi)) { t -= (NTILE - bi); ++bi; }
    const int bj = bi + t;
    const bool diag = (bi == bj);

    const int tid  = threadIdx.x;
    const int wave = tid >> 6;
    const int lane = tid & 63;
    const int quad = lane >> 4;      // 0..3
    const int lcol = lane & 15;      // 0..15
    const int wrow = wave >> 1;      // 0..1
    const int wcol = wave & 1;       // 0..1
    const int ibase = bi * TB;
    const int jbase = bj * TB;

    if (tid < TB)            rlab[tid]      = labels[ibase + tid];
    else if (tid < 2 * TB)   clab[tid - TB] = labels[jbase + tid - TB];

    floatx4 acc[2][2];
#pragma unroll
    for (int mt = 0; mt < 2; ++mt)
#pragma unroll
        for (int nt = 0; nt < 2; ++nt)
            acc[mt][nt] = (floatx4){0.f, 0.f, 0.f, 0.f};

    const char* Eb = (const char*)Ebf;           // row stride = 1024 B
    char* Ab = (char*)Atile;                      // buffer stride 4096 B
    char* Bb = (char*)Btile;
    const char* Bread = diag ? Ab : Bb;
    const int srow = lane >> 2;                       // 0..15
    const int sckb = ((lane & 3) ^ ((lane >> 3) & 3)) * 16;  // swizzled chunk
    const int rdsw = ((lcol >> 1) & 3);               // read-side XOR term

    // Staging: same swizzle as the verified 128-tile kernel (store lane l ->
    // LDS row lane>>2, chunk lane&3 holding global chunk (lane&3)^((row>>1)&3);
    // read XORs the same term). One A (+ one B) global_load_lds per thread:
    // 4 waves x 1KB = 4KB = full 64x32 slab.
#define STAGE(BUF, KT)                                                         \
    do {                                                                       \
        const int kb_ = (KT) * 64;                                             \
        int r_    = wave * 16 + srow;                 /* 0..63 */              \
        int ldso_ = (BUF) * 4096 + wave * 1024 + lane * 16;                    \
        const char* ga_ = Eb + (size_t)(ibase + r_) * (D * 2) + kb_ + sckb;    \
        __builtin_amdgcn_global_load_lds(                                      \
            (const __attribute__((address_space(1))) void*)ga_,                \
            (__attribute__((address_space(3))) void*)(Ab + ldso_), 16, 0, 0);  \
        if (!diag) {                                                           \
            const char* gb_ = Eb + (size_t)(jbase + r_) * (D * 2) + kb_ + sckb;\
            __builtin_amdgcn_global_load_lds(                                  \
                (const __attribute__((address_space(1))) void*)gb_,            \
                (__attribute__((address_space(3))) void*)(Bb + ldso_), 16, 0, 0);\
        }                                                                      \
    } while (0)

    STAGE(0, 0);
    __syncthreads();   // drains vmcnt(0): buffer 0 ready

#pragma unroll 2
    for (int kt = 0; kt < D / 32; ++kt) {
        const int cur = kt & 1;
        if (kt < D / 32 - 1) STAGE(cur ^ 1, kt + 1);   // prefetch next K-slab

        const char* Ar = Ab + cur * 4096;
        const char* Br = (diag ? Ab : Bb) + cur * 4096;

        short8 a[2], b[2];
        const int rchunk = (quad ^ rdsw) * 16;
#pragma unroll
        for (int mt = 0; mt < 2; ++mt) {
            int r = wrow * 32 + mt * 16 + lcol;
            a[mt] = *(const short8*)(Ar + r * 64 + rchunk);
        }
#pragma unroll
        for (int nt = 0; nt < 2; ++nt) {
            int c = wcol * 32 + nt * 16 + lcol;
            b[nt] = *(const short8*)(Br + c * 64 + rchunk);
        }
#pragma unroll
        for (int mt = 0; mt < 2; ++mt)
#pragma unroll
            for (int nt = 0; nt < 2; ++nt)
                acc[mt][nt] = __builtin_amdgcn_mfma_f32_16x16x32_bf16(
                    a[mt], b[nt], acc[mt][nt], 0, 0, 0);

        // ONE barrier per K-step: drains the prefetch (vmcnt) AFTER the
        // MFMA cluster, and gates the buffer swap.
        __syncthreads();
    }
#undef STAGE

    // ---- epilogue ----
    // C layout (m89-verified): col = lane&15, row = quad*4 + reg
    int ljv[2], gjv[2];
#pragma unroll
    for (int nt = 0; nt < 2; ++nt) {
        int cl = wcol * 32 + nt * 16 + lcol;
        ljv[nt] = clab[cl];
        gjv[nt] = jbase + cl;
    }

    float colp[2] = {0.f, 0.f};
    float coln[2] = {0.f, 0.f};

#pragma unroll
    for (int mt = 0; mt < 2; ++mt) {
#pragma unroll
        for (int reg = 0; reg < 4; ++reg) {
            int rl = wrow * 32 + mt * 16 + quad * 4 + reg;
            int gi = ibase + rl;
            int li = rlab[rl];
            float p = 0.f, ng = 0.f;
#pragma unroll
            for (int nt = 0; nt < 2; ++nt) {
                float s = acc[mt][nt][reg];
                if (gi != gjv[nt]) {
                    if (li == ljv[nt]) {
                        float e = __expf(MARGIN - s);          // alpha = 1
                        p += e;  colp[nt] += e;
                    } else {
                        float e = __expf(BETA * (s - MARGIN));
                        ng += e; coln[nt] += e;
                    }
                }
            }
            // row-sum: reduce across the 16 lcol lanes (distinct cols)
            p  += __shfl_xor(p, 1);   ng += __shfl_xor(ng, 1);
            p  += __shfl_xor(p, 2);   ng += __shfl_xor(ng, 2);
            p  += __shfl_xor(p, 4);   ng += __shfl_xor(ng, 4);
            p  += __shfl_xor(p, 8);   ng += __shfl_xor(ng, 8);
            if (lcol == 0) {
                atomicAdd(&pos_sum[gi], p);
                atomicAdd(&neg_sum[gi], ng);
            }
        }
    }

    // col-sum (mirror credit), off-diagonal blocks only:
    // reduce across quads (xor 16,32); lane's col = nt*16+lcol.
    if (!diag) {
#pragma unroll
        for (int nt = 0; nt < 2; ++nt) {
            float cp = colp[nt], cn = coln[nt];
            cp += __shfl_xor(cp, 16);  cn += __shfl_xor(cn, 16);
            cp += __shfl_xor(cp, 32);  cn += __shfl_xor(cn, 32);
            if (quad == 0) {
                int gj = gjv[nt];
                atomicAdd(&pos_sum[gj], cp);
                atomicAdd(&neg_sum[gj], cn);
            }
        }
    }
}

// ---- Kernel 3: finalize (1024 threads: one float4 per thread) ----
__global__ __launch_bounds__(1024) void finalize_kernel(
        const float4* __restrict__ pos4, const float4* __restrict__ neg4,
        float* __restrict__ out) {
    __shared__ float sb[16];
    __shared__ int   sc[16];
    const int tid = threadIdx.x;          // 0..1023 ; N/4 = 1024 float4s
    float4 p  = pos4[tid];
    float4 ng = neg4[tid];
    const float* pp = (const float*)&p;
    const float* nn = (const float*)&ng;
    float tot = 0.f;
    int cnt = 0;
#pragma unroll
    for (int j = 0; j < 4; ++j) {
        if (pp[j] > 0.f && nn[j] > 0.f) {
            tot += log1pf(pp[j]) + (1.0f / BETA) * log1pf(nn[j]);
            cnt += 1;
        }
    }
#pragma unroll
    for (int s = 1; s < 64; s <<= 1) {
        tot += __shfl_xor(tot, s);
        cnt += __shfl_xor(cnt, s);
    }
    if ((tid & 63) == 0) { sb[tid >> 6] = tot; sc[tid >> 6] = cnt; }
    __syncthreads();
    if (tid < 16) {
        float t2 = sb[tid];
        int   c2 = sc[tid];
#pragma unroll
        for (int s = 1; s < 16; s <<= 1) {
            t2 += __shfl_xor(t2, s);
            c2 += __shfl_xor(c2, s);
        }
        if (tid == 0) out[0] = (c2 > 0) ? t2 / (float)c2 : 0.f;
    }
}

extern "C" void kernel_launch(void* const* d_in, const int* in_sizes, int n_in,
                              void* d_out, int out_size, void* d_ws, size_t ws_size,
                              hipStream_t stream) {
    const float* emb   = (const float*)d_in[0];
    const int* labels  = (const int*)d_in[1];
    float* out         = (float*)d_out;

    char* ws = (char*)d_ws;
    unsigned short* Ebf = (unsigned short*)ws;                 // 4 MB
    float* pos_sum = (float*)(ws + (size_t)N * D * 2);         // 16 KB
    float* neg_sum = pos_sum + N;                              // 16 KB

    convert_bf16_kernel<<<(N * D / 4) / 256, 256, 0, stream>>>(
        (const float4*)emb, (ushort4*)Ebf, pos_sum);

    ms_loss_gemm<<<NBLOCKS, 256, 0, stream>>>(Ebf, labels, pos_sum, neg_sum);

    finalize_kernel<<<1, 1024, 0, stream>>>(
        (const float4*)pos_sum, (const float4*)neg_sum, out);
}

// Round 10
// 98.584 us; speedup vs baseline: 1.0864x; 1.0864x over previous
//
#include <hip/hip_runtime.h>
#include <hip/hip_bf16.h>

#define N 4096
#define D 512
#define MARGIN 0.5f
#define BETA 10.0f
#define NT (D / 32)          // 16 K-steps
#define NBLOCKS 528          // upper-triangle 32x32 tiles of 128x128

typedef __attribute__((ext_vector_type(8))) short short8;
typedef __attribute__((ext_vector_type(4))) float floatx4;

__device__ inline unsigned short f2bf(float f) {
    unsigned u = __float_as_uint(f);
    u += 0x7fffu + ((u >> 16) & 1u);   // round-to-nearest-even
    return (unsigned short)(u >> 16);
}

// ---- Kernel 1: f32 -> bf16 convert + zero the accumulator buffers ----
__global__ __launch_bounds__(256) void convert_bf16_kernel(
        const float4* __restrict__ in, ushort4* __restrict__ out,
        float* __restrict__ sums /* 2*N floats to zero */) {
    int idx = blockIdx.x * 256 + threadIdx.x;
    if (idx < 2 * N) sums[idx] = 0.f;
    float4 v = in[idx];
    ushort4 o;
    o.x = f2bf(v.x); o.y = f2bf(v.y); o.z = f2bf(v.z); o.w = f2bf(v.w);
    out[idx] = o;
}

// ---- Kernel 2: fused sim-GEMM + masked exp sums, UPPER-TRIANGLE only ----
//
// HISTORY (do not regress):
//  - R3/R4: fused-finalize __threadfence() was the 4x regression (L2 wb/inv
//    thrash), NOT the counted-vmcnt schedule (R3 == R4 in time). Fusion
//    reverted for good (R5 scoped variant still +4.7us).
//  - R6 64x64 tiles: +18us (work-per-barrier shrank 4x, atomics 2x).
//  - R9 (R7 run): barrier-free loop WITHOUT explicit waits FAILS (inf):
//    with no barrier, the compiler inserts NO vmcnt between global_load_lds
//    and the ds_read of that buffer -> race. The hazard wait must be
//    hand-placed in a barrier-free loop.
//  - Best verified: R2 = 88.85us total (GEMM ~31-36us, ~10x its pipe-busy
//    content; cost = per-K-step vmcnt(0) drain at __syncthreads).
//
// R10: R7's wave-private barrier-free K-loop + the missing counted wait.
//  Each wave double-buffers private A/B slabs (16 KB/wave, 64 KB/block);
//  no cross-wave LDS sharing -> no barrier. Per step:
//    STAGE(next)  (8 global_load_lds/thread)
//    s_waitcnt vmcnt(8)   <- drains exactly the PREVIOUS stage (the buffer
//                            being read); the 8 just-issued stay in flight
//    sched_barrier(0)     <- rule 18: ds_reads must not hoist above the wait
//    ds_read(cur) + 16 MFMA
//  Last iteration peeled with vmcnt(0). Swizzle identical to verified R2.
__global__ __launch_bounds__(256, 2) void ms_loss_gemm(
        const unsigned short* __restrict__ Ebf,
        const int* __restrict__ labels,
        float* __restrict__ pos_sum,
        float* __restrict__ neg_sum) {
    // [wave][buf][A=0/B=1][64 rows x 32 cols bf16] = 65536 B
    __shared__ unsigned short slab[4][2][2][64 * 32];
    __shared__ int rlab[128];
    __shared__ int clab[128];

    // decode linear block id -> upper-triangle tile (bi, bj), bi <= bj
    int t = blockIdx.x;
    int bi = 0;
    while (t >= (32 - bi)) { t -= (32 - bi); ++bi; }
    const int bj = bi + t;
    const bool diag = (bi == bj);

    const int tid  = threadIdx.x;
    const int wave = tid >> 6;
    const int lane = tid & 63;
    const int quad = lane >> 4;      // 0..3
    const int lcol = lane & 15;      // 0..15
    const int wrow = wave >> 1;      // 0..1
    const int wcol = wave & 1;       // 0..1
    const int ibase = bi * 128;
    const int jbase = bj * 128;

    if (tid < 128)       rlab[tid]       = labels[ibase + tid];
    else                 clab[tid - 128] = labels[jbase + tid - 128];

    floatx4 acc[4][4];
#pragma unroll
    for (int mt = 0; mt < 4; ++mt)
#pragma unroll
        for (int nt = 0; nt < 4; ++nt)
            acc[mt][nt] = (floatx4){0.f, 0.f, 0.f, 0.f};

    const char* Eb = (const char*)Ebf;                // row stride = 1024 B
    char* myBase = (char*)&slab[wave][0][0][0];       // buf stride 8192, B at +4096
    const int arow = ibase + wrow * 64;               // wave's A row base in E
    const int brow = jbase + wcol * 64;               // wave's B row base in E
    const int srow = lane >> 2;                       // 0..15 (row within round)
    const int sckb = ((lane & 3) ^ ((lane >> 3) & 3)) * 16;  // swizzled src chunk
    const int rdsw = ((lcol >> 1) & 3);               // read-side XOR term

    // Per-wave STAGE: 4 rounds x (A + B) global_load_lds x16B = 8 loads/thread.
    // LDS row r holds global row base+r; chunk c holds global chunk
    // c ^ (((r&15)>>1)&3) -- same bank-conflict-free swizzle as verified R2.
#define STAGE(BUF, KT)                                                         \
    do {                                                                       \
        const int kb_ = (KT) * 64;                                             \
        char* la_ = myBase + (BUF) * 8192;                                     \
        _Pragma("unroll")                                                      \
        for (int it_ = 0; it_ < 4; ++it_) {                                    \
            int r_  = it_ * 16 + srow;                                         \
            int lo_ = it_ * 1024 + lane * 16;                                  \
            const char* ga_ = Eb + (size_t)(arow + r_) * (D * 2) + kb_ + sckb; \
            __builtin_amdgcn_global_load_lds(                                  \
                (const __attribute__((address_space(1))) void*)ga_,            \
                (__attribute__((address_space(3))) void*)(la_ + lo_), 16, 0, 0);\
            const char* gb_ = Eb + (size_t)(brow + r_) * (D * 2) + kb_ + sckb; \
            __builtin_amdgcn_global_load_lds(                                  \
                (const __attribute__((address_space(1))) void*)gb_,            \
                (__attribute__((address_space(3))) void*)(la_ + 4096 + lo_), 16, 0, 0);\
        }                                                                      \
    } while (0)

#define COMPUTE(CUR)                                                           \
    do {                                                                       \
        const char* Ar = myBase + (CUR) * 8192;                                \
        const char* Br = Ar + 4096;                                            \
        short8 a[4], b[4];                                                     \
        const int rchunk = (quad ^ rdsw) * 16;                                 \
        _Pragma("unroll")                                                      \
        for (int mt = 0; mt < 4; ++mt) {                                       \
            int r = mt * 16 + lcol;                   /* wave-local row */     \
            a[mt] = *(const short8*)(Ar + r * 64 + rchunk);                    \
        }                                                                      \
        _Pragma("unroll")                                                      \
        for (int nt = 0; nt < 4; ++nt) {                                       \
            int c = nt * 16 + lcol;                   /* wave-local col */     \
            b[nt] = *(const short8*)(Br + c * 64 + rchunk);                    \
        }                                                                      \
        _Pragma("unroll")                                                      \
        for (int mt = 0; mt < 4; ++mt)                                         \
            _Pragma("unroll")                                                  \
            for (int nt = 0; nt < 4; ++nt)                                     \
                acc[mt][nt] = __builtin_amdgcn_mfma_f32_16x16x32_bf16(         \
                    a[mt], b[nt], acc[mt][nt], 0, 0, 0);                       \
    } while (0)

    STAGE(0, 0);

    for (int kt = 0; kt < NT - 1; ++kt) {
        STAGE((kt + 1) & 1, kt + 1);
        // Drain exactly the previous stage's 8 loads (the buffer we read
        // now); the 8 just-issued remain in flight. No barrier exists, so
        // this hand wait is the ONLY wait (R9 proved compiler emits none).
        asm volatile("s_waitcnt vmcnt(8)" ::: "memory");
        __builtin_amdgcn_sched_barrier(0);
        COMPUTE(kt & 1);
    }
    asm volatile("s_waitcnt vmcnt(0)" ::: "memory");
    __builtin_amdgcn_sched_barrier(0);
    COMPUTE((NT - 1) & 1);

#undef STAGE
#undef COMPUTE

    __syncthreads();   // rlab/clab visible for the epilogue

    // ---- epilogue ----
    // C layout (m89-verified): col = lane&15, row = quad*4 + reg
    int ljv[4], gjv[4];
#pragma unroll
    for (int nt = 0; nt < 4; ++nt) {
        int cl = wcol * 64 + nt * 16 + lcol;
        ljv[nt] = clab[cl];
        gjv[nt] = jbase + cl;
    }

    float colp[4] = {0.f, 0.f, 0.f, 0.f};
    float coln[4] = {0.f, 0.f, 0.f, 0.f};

#pragma unroll
    for (int mt = 0; mt < 4; ++mt) {
#pragma unroll
        for (int reg = 0; reg < 4; ++reg) {
            int rl = wrow * 64 + mt * 16 + quad * 4 + reg;
            int gi = ibase + rl;
            int li = rlab[rl];
            float p = 0.f, ng = 0.f;
#pragma unroll
            for (int nt = 0; nt < 4; ++nt) {
                float s = acc[mt][nt][reg];
                if (gi != gjv[nt]) {
                    if (li == ljv[nt]) {
                        float e = __expf(MARGIN - s);          // alpha = 1
                        p += e;  colp[nt] += e;
                    } else {
                        float e = __expf(BETA * (s - MARGIN));
                        ng += e; coln[nt] += e;
                    }
                }
            }
            // row-sum: reduce across the 16 lcol lanes (distinct cols)
            p  += __shfl_xor(p, 1);   ng += __shfl_xor(ng, 1);
            p  += __shfl_xor(p, 2);   ng += __shfl_xor(ng, 2);
            p  += __shfl_xor(p, 4);   ng += __shfl_xor(ng, 4);
            p  += __shfl_xor(p, 8);   ng += __shfl_xor(ng, 8);
            if (lcol == 0) {
                atomicAdd(&pos_sum[gi], p);
                atomicAdd(&neg_sum[gi], ng);
            }
        }
    }

    // col-sum (mirror credit), off-diagonal blocks only:
    // reduce across quads (xor 16,32); lane's col = nt*16+lcol.
    if (!diag) {
#pragma unroll
        for (int nt = 0; nt < 4; ++nt) {
            float cp = colp[nt], cn = coln[nt];
            cp += __shfl_xor(cp, 16);  cn += __shfl_xor(cn, 16);
            cp += __shfl_xor(cp, 32);  cn += __shfl_xor(cn, 32);
            if (quad == 0) {
                int gj = gjv[nt];
                atomicAdd(&pos_sum[gj], cp);
                atomicAdd(&neg_sum[gj], cn);
            }
        }
    }
}

// ---- Kernel 3: finalize (1024 threads: one float4 per thread) ----
__global__ __launch_bounds__(1024) void finalize_kernel(
        const float4* __restrict__ pos4, const float4* __restrict__ neg4,
        float* __restrict__ out) {
    __shared__ float sb[16];
    __shared__ int   sc[16];
    const int tid = threadIdx.x;          // 0..1023 ; N/4 = 1024 float4s
    float4 p  = pos4[tid];
    float4 ng = neg4[tid];
    const float* pp = (const float*)&p;
    const float* nn = (const float*)&ng;
    float tot = 0.f;
    int cnt = 0;
#pragma unroll
    for (int j = 0; j < 4; ++j) {
        if (pp[j] > 0.f && nn[j] > 0.f) {
            tot += log1pf(pp[j]) + (1.0f / BETA) * log1pf(nn[j]);
            cnt += 1;
        }
    }
#pragma unroll
    for (int s = 1; s < 64; s <<= 1) {
        tot += __shfl_xor(tot, s);
        cnt += __shfl_xor(cnt, s);
    }
    if ((tid & 63) == 0) { sb[tid >> 6] = tot; sc[tid >> 6] = cnt; }
    __syncthreads();
    if (tid < 16) {
        float t2 = sb[tid];
        int   c2 = sc[tid];
#pragma unroll
        for (int s = 1; s < 16; s <<= 1) {
            t2 += __shfl_xor(t2, s);
            c2 += __shfl_xor(c2, s);
        }
        if (tid == 0) out[0] = (c2 > 0) ? t2 / (float)c2 : 0.f;
    }
}

extern "C" void kernel_launch(void* const* d_in, const int* in_sizes, int n_in,
                              void* d_out, int out_size, void* d_ws, size_t ws_size,
                              hipStream_t stream) {
    const float* emb   = (const float*)d_in[0];
    const int* labels  = (const int*)d_in[1];
    float* out         = (float*)d_out;

    char* ws = (char*)d_ws;
    unsigned short* Ebf = (unsigned short*)ws;                 // 4 MB
    float* pos_sum = (float*)(ws + (size_t)N * D * 2);         // 16 KB
    float* neg_sum = pos_sum + N;                              // 16 KB

    convert_bf16_kernel<<<(N * D / 4) / 256, 256, 0, stream>>>(
        (const float4*)emb, (ushort4*)Ebf, pos_sum);

    ms_loss_gemm<<<NBLOCKS, 256, 0, stream>>>(Ebf, labels, pos_sum, neg_sum);

    finalize_kernel<<<1, 1024, 0, stream>>>(
        (const float4*)pos_sum, (const float4*)neg_sum, out);
}